// Round 9
// baseline (5919.856 us; speedup 1.0000x reference)
//
#include <hip/hip_runtime.h>

#define LSEQ 2048
#define NB 24
#define NH 75
#define G3 225
#define NIN 500
#define OUTW 450

typedef _Float16 h2 __attribute__((ext_vector_type(2)));
typedef _Float16 h8 __attribute__((ext_vector_type(8)));
typedef float f4 __attribute__((ext_vector_type(4)));

__device__ __forceinline__ h2 pkrtz(float a, float b) {
  return __builtin_bit_cast(h2, __builtin_amdgcn_cvt_pkrtz(a, b));
}
__device__ __forceinline__ float dot2(h2 a, h2 b, float c) {
  return __builtin_amdgcn_fdot2(a, b, c, false);
}
// 8-wide half dot: pairs align to dwords, so extracts are free sub-reg refs
__device__ __forceinline__ float dot8(h8 w, h8 x, float c) {
  h2 w0{w[0], w[1]}, w1{w[2], w[3]}, w2{w[4], w[5]}, w3{w[6], w[7]};
  h2 x0{x[0], x[1]}, x1{x[2], x[3]}, x2{x[4], x[5]}, x3{x[6], x[7]};
  c = dot2(w0, x0, c);
  c = dot2(w1, x1, c);
  c = dot2(w2, x2, c);
  c = dot2(w3, x3, c);
  return c;
}
__device__ __forceinline__ h8 ld8f(const float* p, int base, int n) {
  h8 o;
#pragma unroll
  for (int i = 0; i < 8; i += 2) {
    float a = (base + i < n) ? p[base + i] : 0.f;
    float b = (base + i + 1 < n) ? p[base + i + 1] : 0.f;
    h2 t = pkrtz(a, b);
    o[i] = t[0];
    o[i + 1] = t[1];
  }
  return o;
}
__device__ __forceinline__ h8 zero8() {
  h8 v;
#pragma unroll
  for (int i = 0; i < 8; i++) v[i] = (_Float16)0;
  return v;
}
__device__ __forceinline__ float sigm(float x) {
  return __builtin_amdgcn_rcpf(1.f + __builtin_amdgcn_exp2f(-1.4426950408889634f * x));
}
__device__ __forceinline__ float tanh_f(float x) {
  float xx = fminf(x, 15.f);
  float e = __builtin_amdgcn_exp2f(2.8853900817779268f * xx);
  return (e - 1.f) * __builtin_amdgcn_rcpf(e + 1.f);
}

// device-scope relaxed (sc1, no cache-maintenance ops)
__device__ __forceinline__ float ldg_dev(const float* p) {
  return __hip_atomic_load(p, __ATOMIC_RELAXED, __HIP_MEMORY_SCOPE_AGENT);
}
__device__ __forceinline__ void stg_dev(float* p, float v) {
  __hip_atomic_store(p, v, __ATOMIC_RELAXED, __HIP_MEMORY_SCOPE_AGENT);
}
__device__ __forceinline__ int ldflag(const int* p) {
  return __hip_atomic_load(p, __ATOMIC_RELAXED, __HIP_MEMORY_SCOPE_AGENT);
}
__device__ __forceinline__ void stflag(int* p, int v) {
  __hip_atomic_store(p, v, __ATOMIC_RELAXED, __HIP_MEMORY_SCOPE_AGENT);
}

#define PIN4(a, b, c, d) asm("" : "+v"(a), "+v"(b), "+v"(c), "+v"(d))
#define PIN2(a, b) asm("" : "+v"(a), "+v"(b))

// Raw workgroup barrier: does NOT drain vmcnt.
// LDS producer->consumer ordering needs lgkmcnt(0) on the writer side;
// sched_barrier(0) pins the instruction scheduler on both sides (rule #18).
#define WG_BARRIER()                                     \
  do {                                                   \
    asm volatile("s_waitcnt lgkmcnt(0)" ::: "memory");   \
    __builtin_amdgcn_sched_barrier(0);                   \
    __builtin_amdgcn_s_barrier();                        \
    __builtin_amdgcn_sched_barrier(0);                   \
  } while (0)

// ---------------- init flags ----------------
__global__ void init_flags(int* f) {
  if (threadIdx.x < 144) stflag(&f[threadIdx.x], 0);
}

// ---------------- kernel A: gx GEMM (unchanged, it works) ----------------
__device__ __forceinline__ void load8_guard(float* v, const float* src, int kbase, bool rowvalid) {
  if (rowvalid && (kbase + 8 <= NIN)) {
    f4 t0 = *(const f4*)(src);
    f4 t1 = *(const f4*)(src + 4);
    v[0] = t0[0]; v[1] = t0[1]; v[2] = t0[2]; v[3] = t0[3];
    v[4] = t1[0]; v[5] = t1[1]; v[6] = t1[2]; v[7] = t1[3];
  } else {
#pragma unroll
    for (int i = 0; i < 8; i++) v[i] = (rowvalid && (kbase + i < NIN)) ? src[i] : 0.f;
  }
}
__device__ __forceinline__ void pack8_store(_Float16* dst, const float* v) {
  h2 a = pkrtz(v[0], v[1]);
  h2 b = pkrtz(v[2], v[3]);
  h2 c = pkrtz(v[4], v[5]);
  h2 d = pkrtz(v[6], v[7]);
  h8 o;
  o[0] = a[0]; o[1] = a[1]; o[2] = b[0]; o[3] = b[1];
  o[4] = c[0]; o[5] = c[1]; o[6] = d[0]; o[7] = d[1];
  *(h8*)dst = o;
}

__global__ __launch_bounds__(256) void gemm_gx(const float* __restrict__ x,
                                               const float* __restrict__ w,
                                               const float* __restrict__ bias,
                                               float* __restrict__ out) {
  __shared__ __align__(16) _Float16 xs[64 * 40];
  __shared__ __align__(16) _Float16 wsh[464 * 40];
  const int tid = threadIdx.x;
  const int blk = blockIdx.x;
  const int lane = tid & 63, wid = tid >> 6;
  const int q = lane >> 4, cn = lane & 15;
  const int r = tid >> 2, kq = tid & 3;

  f4 acc[29];
#pragma unroll
  for (int j = 0; j < 29; j++) acc[j] = f4{0.f, 0.f, 0.f, 0.f};

  for (int kc = 0; kc < 16; kc++) {
    const int kbase = kc * 32 + kq * 8;
    {
      const float* src = x + (size_t)(blk * 64 + r) * NIN + kbase;
      float v[8];
      load8_guard(v, src, kbase, true);
      pack8_store(&xs[r * 40 + kq * 8], v);
    }
#pragma unroll
    for (int it = 0; it < 8; it++) {
      int rr = r + it * 64;
      if (rr < 464) {
        const float* src = w + (size_t)rr * NIN + kbase;
        float v[8];
        load8_guard(v, src, kbase, rr < OUTW);
        pack8_store(&wsh[rr * 40 + kq * 8], v);
      }
    }
    __syncthreads();
    h8 a = *(const h8*)&xs[(wid * 16 + cn) * 40 + q * 8];
#pragma unroll
    for (int j = 0; j < 29; j++) {
      h8 bf = *(const h8*)&wsh[(j * 16 + cn) * 40 + q * 8];
      acc[j] = __builtin_amdgcn_mfma_f32_16x16x32_f16(a, bf, acc[j], 0, 0, 0);
    }
    __syncthreads();
  }
#pragma unroll
  for (int j = 0; j < 29; j++) {
    int n = j * 16 + cn;
    float bv = (n < OUTW) ? bias[n] : 0.f;
#pragma unroll
    for (int rr = 0; rr < 4; rr++) {
      float val = acc[j][rr] + bv;
      float partner = __shfl_xor(val, 1, 64);
      if (((lane & 1) == 0) && n < OUTW) {
        h2 pk = pkrtz(val, partner);
        int mg = blk * 64 + wid * 16 + q * 4 + rr;
        out[(size_t)mg * OUTW + G3 + (n >> 1)] = __builtin_bit_cast(float, pk);
      }
    }
  }
}

// ---------------- kernel B: persistent GRU scan ----------------
// R9 = R8 body with the VGPR CAP ACTUALLY LIFTED.
// Evidence trail: R7 (512,2)+waves_per_eu(2) -> VGPR 128 (16 waves/CU
// demanded -> 4/EU -> 512/4=128). R8 bare launch_bounds(512) -> STILL 128:
// the backend's DEFAULT waves-per-eu target is 4. Both spilled the ~116
// pinned weight VGPRs (FETCH +40MB, VALUBusy 4.3%, 2.2x regression).
// Fix: declare the true floor explicitly -> 2 waves/EU (what one 512-thread
// WG already forces) => maxVGPR = 512/2 = 256, enough for the ~188 this
// code shape allocates:
//   __launch_bounds__(512, 1)  : 1 WG/CU -> 8 waves/CU -> 2/EU -> cap 256
//   amdgpu_waves_per_eu(2)     : LLVM range min 2 -> cap 256 directly
// PASS SIGNAL: VGPR_Count >= 180 in the counter CSV. If still 128, the
// 512-fusion is compiler-hostile -> revert to R5 structure next round.
// 72 WGs = cell c (0..5) x batch-pair g (0..11); 512 threads.
//   bg = tid>>8 selects batch b = g*2+bg; t8 = tid&255 is the role index,
//   byte-identical to R5 within a group (same lanes, same summation order).
// Sync scheme per batch unchanged from R5.
__global__ __launch_bounds__(512, 1) __attribute__((amdgpu_waves_per_eu(2)))
void scan_gru(const float* __restrict__ h0,
              const float* __restrict__ w_hh0, const float* __restrict__ b_hh0,
              const float* __restrict__ w_ih12, const float* __restrict__ w_hh12,
              const float* __restrict__ b_ih12, const float* __restrict__ b_hh12,
              float* __restrict__ out, int* flags) {
  __shared__ __align__(16) float A_s[2][232], B_s[2][232];
  __shared__ __align__(16) _Float16 h16[2][80];
  __shared__ __align__(16) _Float16 xr[2][16][152];

  const int bi = blockIdx.x;
  if (bi >= 72) return;
  const int tid = threadIdx.x;
  const int bg = tid >> 8;          // batch sub-group 0/1
  const int t8 = tid & 255;         // role index within group (== R5 tid)
  const int c = bi / 12;            // cell
  const int b = (bi % 12) * 2 + bg; // batch
  const int l = c >> 1, d = c & 1;
  const int ci = (l - 1) * 2 + d;   // index into *_12 arrays (l>=1)
  const int u0 = (l - 1) * 2;       // upstream cell pair

  const bool isgate = (t8 < G3);    // one row per lane: row = t8
  const bool ish = (t8 < NH);       // hj = t8
  const int hj = t8;
  const int s = t8 - 225;
  const bool issync = (s >= 0) && (s < 30) && (l >= 1);

#define SYNC_LOAD20(Pr, base)                                                            \
  do {                                                                                   \
    _Pragma("unroll") for (int i = 0; i < 20; i++) {                                     \
      int qq = s * 20 + i;                                                               \
      int tt = (base) + qq / 150;                                                        \
      int rem = qq % 150;                                                                \
      Pr[i >> 2][i & 3] = ldg_dev(&out[((size_t)tt * NB + b) * OUTW + u0 * NH + rem]);   \
    }                                                                                    \
  } while (0)

#define SYNC_STORE20(Pr, base)                                                           \
  do {                                                                                   \
    _Pragma("unroll") for (int i = 0; i < 20; i++) {                                     \
      int qq = s * 20 + i;                                                               \
      int tt = (base) + qq / 150;                                                        \
      int rem = qq % 150;                                                                \
      xr[bg][tt & 15][rem] = (_Float16)Pr[i >> 2][i & 3];                                \
    }                                                                                    \
  } while (0)

  // ---- weights, ONE row per gate lane ----
  h8 Wa0 = zero8(), Wa1 = zero8(), Wa2 = zero8(), Wa3 = zero8(), Wa4 = zero8();
  h8 Wa5 = zero8(), Wa6 = zero8(), Wa7 = zero8(), Wa8 = zero8(), Wa9 = zero8();
  h8 Ua0 = zero8(), Ua1 = zero8(), Ua2 = zero8(), Ua3 = zero8(), Ua4 = zero8();
  h8 Ua5 = zero8(), Ua6 = zero8(), Ua7 = zero8(), Ua8 = zero8(), Ua9 = zero8();
  h8 Ua10 = zero8(), Ua11 = zero8(), Ua12 = zero8(), Ua13 = zero8(), Ua14 = zero8();
  h8 Ua15 = zero8(), Ua16 = zero8(), Ua17 = zero8(), Ua18 = zero8();
  float bhha = 0.f, biha = 0.f;

  // a-dot chain for x(t+1): SAME accumulation order as R5 -> identical rounding.
#define A_DOTS(dst, slot)                                                     \
  do {                                                                        \
    const h8* xv = (const h8*)xr[bg][slot];                                   \
    h8 X0 = xv[0], X1 = xv[1], X2 = xv[2], X3 = xv[3], X4 = xv[4];            \
    h8 X5 = xv[5], X6 = xv[6], X7 = xv[7], X8 = xv[8], X9 = xv[9];            \
    h8 X10 = xv[10], X11 = xv[11], X12 = xv[12], X13 = xv[13], X14 = xv[14];  \
    h8 X15 = xv[15], X16 = xv[16], X17 = xv[17], X18 = xv[18];                \
    float a0a = dot8(Ua0, X0, biha), a0b = dot8(Ua1, X1, 0.f);                \
    a0a = dot8(Ua2, X2, a0a);   a0b = dot8(Ua3, X3, a0b);                     \
    a0a = dot8(Ua4, X4, a0a);   a0b = dot8(Ua5, X5, a0b);                     \
    a0a = dot8(Ua6, X6, a0a);   a0b = dot8(Ua7, X7, a0b);                     \
    a0a = dot8(Ua8, X8, a0a);   a0b = dot8(Ua9, X9, a0b);                     \
    a0a = dot8(Ua10, X10, a0a); a0b = dot8(Ua11, X11, a0b);                   \
    a0a = dot8(Ua12, X12, a0a); a0b = dot8(Ua13, X13, a0b);                   \
    a0a = dot8(Ua14, X14, a0a); a0b = dot8(Ua15, X15, a0b);                   \
    a0a = dot8(Ua16, X16, a0a); a0b = dot8(Ua17, X17, a0b);                   \
    a0a = dot8(Ua18, X18, a0a);                                               \
    dst = a0a + a0b;                                                          \
  } while (0)

  if (isgate) {
    const int row = t8;
    const float* wA = (l == 0) ? w_hh0 + (size_t)(d * G3 + row) * NH
                               : w_hh12 + (size_t)(ci * G3 + row) * NH;
    Wa0 = ld8f(wA, 0, NH);  Wa1 = ld8f(wA, 8, NH);  Wa2 = ld8f(wA, 16, NH);
    Wa3 = ld8f(wA, 24, NH); Wa4 = ld8f(wA, 32, NH); Wa5 = ld8f(wA, 40, NH);
    Wa6 = ld8f(wA, 48, NH); Wa7 = ld8f(wA, 56, NH); Wa8 = ld8f(wA, 64, NH);
    Wa9 = ld8f(wA, 72, NH);
    bhha = (l == 0) ? b_hh0[d * G3 + row] : b_hh12[ci * G3 + row];
    if (l > 0) {
      const float* uA = w_ih12 + (size_t)(ci * G3 + row) * (2 * NH);
      Ua0 = ld8f(uA, 0, 150);   Ua1 = ld8f(uA, 8, 150);   Ua2 = ld8f(uA, 16, 150);
      Ua3 = ld8f(uA, 24, 150);  Ua4 = ld8f(uA, 32, 150);  Ua5 = ld8f(uA, 40, 150);
      Ua6 = ld8f(uA, 48, 150);  Ua7 = ld8f(uA, 56, 150);  Ua8 = ld8f(uA, 64, 150);
      Ua9 = ld8f(uA, 72, 150);  Ua10 = ld8f(uA, 80, 150); Ua11 = ld8f(uA, 88, 150);
      Ua12 = ld8f(uA, 96, 150); Ua13 = ld8f(uA, 104, 150); Ua14 = ld8f(uA, 112, 150);
      Ua15 = ld8f(uA, 120, 150); Ua16 = ld8f(uA, 128, 150); Ua17 = ld8f(uA, 136, 150);
      Ua18 = ld8f(uA, 144, 150);
      biha = b_ih12[ci * G3 + row];
    }
  }

  float hreg = 0.f, hh0 = 0.f, hh1 = 0.f, hh2 = 0.f;
  if (ish) {
    hreg = h0[(size_t)(c * NB + b) * NH + hj];
    h16[bg][hj] = (_Float16)hreg;
  }
  if (t8 >= 225 && t8 < 230) h16[bg][NH + (t8 - 225)] = (_Float16)0;
  if (t8 < 16) { xr[bg][t8][150] = (_Float16)0; xr[bg][t8][151] = (_Float16)0; }

  // sync-lane double-buffer prefetch regs (const-indexed only)
  f4 PA[5], PB[5];
#pragma unroll
  for (int i = 0; i < 5; i++) { PA[i] = f4{0.f, 0.f, 0.f, 0.f}; PB[i] = f4{0.f, 0.f, 0.f, 0.f}; }

  const int* f0p = (l >= 1) ? &flags[u0 * NB + b] : flags;
  const int* f1p = (l >= 1) ? &flags[(u0 + 1) * NB + b] : flags;
  int fv0 = 0, fv1 = 0;

  // prologue: fill ring times 0..7 directly, preload PB with times 8..11,
  // then pre-verify flag>=16 (covers t=0's PA load of times 12..15).
  if (issync) {
    for (int p = 0; p < 2; p++) {
      while (ldflag(f0p) < 4 * p + 4 || ldflag(f1p) < 4 * p + 4) {}
#pragma unroll
      for (int i = 0; i < 20; i++) {
        int q = s * 20 + i;
        int tt = 4 * p + q / 150;
        int rem = q % 150;
        float v = ldg_dev(&out[((size_t)tt * NB + b) * OUTW + u0 * NH + rem]);
        xr[bg][tt & 15][rem] = (_Float16)v;
      }
    }
    while (ldflag(f0p) < 12 || ldflag(f1p) < 12) {}
    SYNC_LOAD20(PB, 8);
    while (ldflag(f0p) < 16 || ldflag(f1p) < 16) {}
    fv0 = 16; fv1 = 16;
  }

  // prologue: layer-0 gx(0) raw dword (extracted at first consumption)
  const int n0 = d * G3 + t8;  // gx element index for l==0 gate lanes
  float cr = 0.f;
  if (l == 0 && isgate) {
    cr = out[(size_t)b * OUTW + G3 + (n0 >> 1)];
  }
  __syncthreads();  // ring slots 0..7 now visible to all lanes

  // prologue: xa(0) = U.x(0) from ring slot 0 (l>=1 gate lanes)
  float xa = 0.f;
  if (l > 0 && isgate) {
    A_DOTS(xa, 0);
  }

  for (int t = 0; t < LSEQ; t++) {
    // ================= P1 =================
    if (isgate) {
      // x-part is precomputed (xa): store it FIRST so the A_s write latency
      // hides under the W-dots that follow.
      if (l > 0) A_s[bg][t8] = xa;
      // keep W weights register-resident (defeat remat/reload)
      PIN4(Wa0, Wa1, Wa2, Wa3); PIN4(Wa4, Wa5, Wa6, Wa7); PIN2(Wa8, Wa9);
      const h8* hv = (const h8*)h16[bg];
      h8 H0 = hv[0], H1 = hv[1], H2 = hv[2], H3 = hv[3], H4 = hv[4];
      h8 H5 = hv[5], H6 = hv[6], H7 = hv[7], H8 = hv[8], H9 = hv[9];
      float b0a = dot8(Wa0, H0, bhha), b0b = dot8(Wa1, H1, 0.f);
      b0a = dot8(Wa2, H2, b0a); b0b = dot8(Wa3, H3, b0b);
      b0a = dot8(Wa4, H4, b0a); b0b = dot8(Wa5, H5, b0b);
      b0a = dot8(Wa6, H6, b0a); b0b = dot8(Wa7, H7, b0b);
      b0a = dot8(Wa8, H8, b0a); b0b = dot8(Wa9, H9, b0b);
      float accB = b0a + b0b;
      if (l == 0) {
        // consume gx(t) from the raw dword loaded LAST step (full-step window)
        h2 pc = __builtin_bit_cast(h2, cr);
        float accA = (n0 & 1) ? (float)pc[1] : (float)pc[0];
        A_s[bg][t8] = accA;
        // then issue the load for gx(t+1) into the same loop-carried reg
        if (t + 1 < LSEQ) {
          cr = out[((size_t)(t + 1) * NB + b) * OUTW + G3 + (n0 >> 1)];
        }
      }
      B_s[bg][t8] = accB;
    }
    if (issync && (t & 3) == 0) {
      // (1) retire the 4-step-old prefetch into the ring (times t+8..t+11)
      if (t + 8 < LSEQ) {
        if (t & 4) SYNC_STORE20(PA, t + 8); else SYNC_STORE20(PB, t + 8);
      }
      // (2) flag check for the batch loaded below (times t+16..t+19 needs
      //     flag >= t+20): compare speculative values; spin only on miss.
      if (t + 20 <= LSEQ) {
        int need = t + 20;
        if (fv0 < need || fv1 < need) {
          while (ldflag(f0p) < need || ldflag(f1p) < need) {}
        }
      }
      // (3) issue fresh prefetch (times t+12..t+15); consumed at t+4.
      if (t + 12 < LSEQ) {
        if (t & 4) SYNC_LOAD20(PB, t + 12); else SYNC_LOAD20(PA, t + 12);
      }
      // (4) speculative flag reads for the check at t+4 (need = t+24).
      if (t + 24 <= LSEQ) {
        fv0 = ldflag(f0p);
        fv1 = ldflag(f1p);
      }
    }
    // publish F = t-4: stores <= t-5 were vmcnt(4)-confirmed at step t-1 P2,
    // and barrier2 of t-1 ordered that before this store.
    if (t8 == 0 && c < 4 && (t & 3) == 0 && t >= 8) stflag(&flags[c * NB + b], t - 4);
    WG_BARRIER();  // barrier1 (lgkm-only; vmem stays in flight)

    // ================= P2 =================
    if (ish) {
      float rg = sigm(A_s[bg][hj] + B_s[bg][hj]);
      float zg = sigm(A_s[bg][NH + hj] + B_s[bg][NH + hj]);
      float ng = tanh_f(A_s[bg][2 * NH + hj] + rg * B_s[bg][2 * NH + hj]);
      float hn = (1.f - zg) * ng + zg * hreg;
      hreg = hn;
      h16[bg][hj] = (_Float16)hn;
      hh0 = ((t & 3) == 0) ? hn : hh0;
      hh1 = ((t & 3) == 1) ? hn : hh1;
      hh2 = ((t & 3) == 2) ? hn : hh2;
      if ((t & 3) == 3) {
        float* base = out + (size_t)(t - 3) * NB * OUTW + (size_t)b * OUTW + c * NH + hj;
        stg_dev(base, hh0);
        stg_dev(base + (size_t)NB * OUTW, hh1);
        stg_dev(base + 2 * (size_t)NB * OUTW, hh2);
        stg_dev(base + 3 * (size_t)NB * OUTW, hn);
        // counted drain: all store batches OLDER than these 4 are now
        // globally visible (vmcnt retires in issue order). ~0 actual wait.
        asm volatile("s_waitcnt vmcnt(4)" ::: "memory");
      }
    }
    // a-dots for step t+1, OFF the serial path: x(t+1) is ring-resident
    // (slot (t+1)&15; sync stores this step touch slots (t+8..t+11)&15 —
    // disjoint). Idle gate lanes absorb this; h-lanes interleave it with
    // their latency-bound activation chain.
    if (l > 0 && isgate && (t + 1 < LSEQ)) {
      PIN4(Ua0, Ua1, Ua2, Ua3); PIN4(Ua4, Ua5, Ua6, Ua7); PIN4(Ua8, Ua9, Ua10, Ua11);
      PIN4(Ua12, Ua13, Ua14, Ua15); PIN2(Ua16, Ua17); asm("" : "+v"(Ua18));
      A_DOTS(xa, (t + 1) & 15);
    }
    WG_BARRIER();  // barrier2 (orders h16/A_s reuse and the vmcnt(4) above)
  }
  __syncthreads();  // full drain (incl. last h-store batch) before final publish
  if (t8 == 0 && c < 4) stflag(&flags[c * NB + b], LSEQ);
}

extern "C" void kernel_launch(void* const* d_in, const int* in_sizes, int n_in,
                              void* d_out, int out_size, void* d_ws, size_t ws_size,
                              hipStream_t stream) {
  const float* x      = (const float*)d_in[0];
  const float* h0     = (const float*)d_in[1];
  const float* w_ih0  = (const float*)d_in[2];
  const float* w_hh0  = (const float*)d_in[3];
  const float* b_ih0  = (const float*)d_in[4];
  const float* b_hh0  = (const float*)d_in[5];
  const float* w_ih12 = (const float*)d_in[6];
  const float* w_hh12 = (const float*)d_in[7];
  const float* b_ih12 = (const float*)d_in[8];
  const float* b_hh12 = (const float*)d_in[9];
  float* out = (float*)d_out;
  int* flags = (int*)d_ws;

  hipLaunchKernelGGL(init_flags, dim3(1), dim3(256), 0, stream, flags);
  hipLaunchKernelGGL(gemm_gx, dim3(768), dim3(256), 0, stream, x, w_ih0, b_ih0, out);
  hipLaunchKernelGGL(scan_gru, dim3(72), dim3(512), 0, stream,
                     h0, w_hh0, b_hh0, w_ih12, w_hh12, b_ih12, b_hh12, out, flags);
}

// Round 10
// 2742.661 us; speedup vs baseline: 2.1584x; 2.1584x over previous
//
#include <hip/hip_runtime.h>

#define LSEQ 2048
#define NB 24
#define NH 75
#define G3 225
#define NIN 500
#define OUTW 450
#define NRING 32
#define RINGSTRIDE (96 * 225)  // floats per ring slot: 4 cells x 24 batches x 225 rows

typedef _Float16 h2 __attribute__((ext_vector_type(2)));
typedef _Float16 h8 __attribute__((ext_vector_type(8)));
typedef float f4 __attribute__((ext_vector_type(4)));

__device__ __forceinline__ h2 pkrtz(float a, float b) {
  return __builtin_bit_cast(h2, __builtin_amdgcn_cvt_pkrtz(a, b));
}
__device__ __forceinline__ float dot2(h2 a, h2 b, float c) {
  return __builtin_amdgcn_fdot2(a, b, c, false);
}
__device__ __forceinline__ float dot8(h8 w, h8 x, float c) {
  h2 w0{w[0], w[1]}, w1{w[2], w[3]}, w2{w[4], w[5]}, w3{w[6], w[7]};
  h2 x0{x[0], x[1]}, x1{x[2], x[3]}, x2{x[4], x[5]}, x3{x[6], x[7]};
  c = dot2(w0, x0, c);
  c = dot2(w1, x1, c);
  c = dot2(w2, x2, c);
  c = dot2(w3, x3, c);
  return c;
}
__device__ __forceinline__ h8 ld8f(const float* p, int base, int n) {
  h8 o;
#pragma unroll
  for (int i = 0; i < 8; i += 2) {
    float a = (base + i < n) ? p[base + i] : 0.f;
    float b = (base + i + 1 < n) ? p[base + i + 1] : 0.f;
    h2 t = pkrtz(a, b);
    o[i] = t[0];
    o[i + 1] = t[1];
  }
  return o;
}
__device__ __forceinline__ h8 zero8() {
  h8 v;
#pragma unroll
  for (int i = 0; i < 8; i++) v[i] = (_Float16)0;
  return v;
}
__device__ __forceinline__ float sigm(float x) {
  return __builtin_amdgcn_rcpf(1.f + __builtin_amdgcn_exp2f(-1.4426950408889634f * x));
}
__device__ __forceinline__ float tanh_f(float x) {
  float xx = fminf(x, 15.f);
  float e = __builtin_amdgcn_exp2f(2.8853900817779268f * xx);
  return (e - 1.f) * __builtin_amdgcn_rcpf(e + 1.f);
}

// device-scope relaxed (sc1)
__device__ __forceinline__ float ldg_dev(const float* p) {
  return __hip_atomic_load(p, __ATOMIC_RELAXED, __HIP_MEMORY_SCOPE_AGENT);
}
__device__ __forceinline__ void stg_dev(float* p, float v) {
  __hip_atomic_store(p, v, __ATOMIC_RELAXED, __HIP_MEMORY_SCOPE_AGENT);
}
__device__ __forceinline__ int ldflag(const int* p) {
  return __hip_atomic_load(p, __ATOMIC_RELAXED, __HIP_MEMORY_SCOPE_AGENT);
}
__device__ __forceinline__ void stflag(int* p, int v) {
  __hip_atomic_store(p, v, __ATOMIC_RELAXED, __HIP_MEMORY_SCOPE_AGENT);
}

#define PIN4(a, b, c, d) asm("" : "+v"(a), "+v"(b), "+v"(c), "+v"(d))
#define PIN2(a, b) asm("" : "+v"(a), "+v"(b))

// Raw workgroup barrier: lgkm-only drain; vmem stays in flight (rule #18 fences).
#define WG_BARRIER()                                     \
  do {                                                   \
    asm volatile("s_waitcnt lgkmcnt(0)" ::: "memory");   \
    __builtin_amdgcn_sched_barrier(0);                   \
    __builtin_amdgcn_s_barrier();                        \
    __builtin_amdgcn_sched_barrier(0);                   \
  } while (0)

// ---------------- init flags ----------------
// flags[0..143]   : scan progress / h availability per (cell c, b): value v => h(times <= v-1) stored.
// flags[144..239] : helper A availability per (cell c>=2, b): value v => A(times <= v-1) stored.
__global__ void init_flags(int* f) {
  if (threadIdx.x < 240) stflag(&f[threadIdx.x], 0);
}

// ---------------- kernel A: gx GEMM (unchanged, it works) ----------------
__device__ __forceinline__ void load8_guard(float* v, const float* src, int kbase, bool rowvalid) {
  if (rowvalid && (kbase + 8 <= NIN)) {
    f4 t0 = *(const f4*)(src);
    f4 t1 = *(const f4*)(src + 4);
    v[0] = t0[0]; v[1] = t0[1]; v[2] = t0[2]; v[3] = t0[3];
    v[4] = t1[0]; v[5] = t1[1]; v[6] = t1[2]; v[7] = t1[3];
  } else {
#pragma unroll
    for (int i = 0; i < 8; i++) v[i] = (rowvalid && (kbase + i < NIN)) ? src[i] : 0.f;
  }
}
__device__ __forceinline__ void pack8_store(_Float16* dst, const float* v) {
  h2 a = pkrtz(v[0], v[1]);
  h2 b = pkrtz(v[2], v[3]);
  h2 c = pkrtz(v[4], v[5]);
  h2 d = pkrtz(v[6], v[7]);
  h8 o;
  o[0] = a[0]; o[1] = a[1]; o[2] = b[0]; o[3] = b[1];
  o[4] = c[0]; o[5] = c[1]; o[6] = d[0]; o[7] = d[1];
  *(h8*)dst = o;
}

__global__ __launch_bounds__(256) void gemm_gx(const float* __restrict__ x,
                                               const float* __restrict__ w,
                                               const float* __restrict__ bias,
                                               float* __restrict__ out) {
  __shared__ __align__(16) _Float16 xs[64 * 40];
  __shared__ __align__(16) _Float16 wsh[464 * 40];
  const int tid = threadIdx.x;
  const int blk = blockIdx.x;
  const int lane = tid & 63, wid = tid >> 6;
  const int q = lane >> 4, cn = lane & 15;
  const int r = tid >> 2, kq = tid & 3;

  f4 acc[29];
#pragma unroll
  for (int j = 0; j < 29; j++) acc[j] = f4{0.f, 0.f, 0.f, 0.f};

  for (int kc = 0; kc < 16; kc++) {
    const int kbase = kc * 32 + kq * 8;
    {
      const float* src = x + (size_t)(blk * 64 + r) * NIN + kbase;
      float v[8];
      load8_guard(v, src, kbase, true);
      pack8_store(&xs[r * 40 + kq * 8], v);
    }
#pragma unroll
    for (int it = 0; it < 8; it++) {
      int rr = r + it * 64;
      if (rr < 464) {
        const float* src = w + (size_t)rr * NIN + kbase;
        float v[8];
        load8_guard(v, src, kbase, rr < OUTW);
        pack8_store(&wsh[rr * 40 + kq * 8], v);
      }
    }
    __syncthreads();
    h8 a = *(const h8*)&xs[(wid * 16 + cn) * 40 + q * 8];
#pragma unroll
    for (int j = 0; j < 29; j++) {
      h8 bf = *(const h8*)&wsh[(j * 16 + cn) * 40 + q * 8];
      acc[j] = __builtin_amdgcn_mfma_f32_16x16x32_f16(a, bf, acc[j], 0, 0, 0);
    }
    __syncthreads();
  }
#pragma unroll
  for (int j = 0; j < 29; j++) {
    int n = j * 16 + cn;
    float bv = (n < OUTW) ? bias[n] : 0.f;
#pragma unroll
    for (int rr = 0; rr < 4; rr++) {
      float val = acc[j][rr] + bv;
      float partner = __shfl_xor(val, 1, 64);
      if (((lane & 1) == 0) && n < OUTW) {
        h2 pk = pkrtz(val, partner);
        int mg = blk * 64 + wid * 16 + q * 4 + rr;
        out[(size_t)mg * OUTW + G3 + (n >> 1)] = __builtin_bit_cast(float, pk);
      }
    }
  }
}

// ---------------- kernel B: scan (144 WGs) + U.x helpers (96 WGs), one launch ----------------
// R10: producer/consumer WG specialization. The 512-fusion is dead (VGPR capped
// at 128 for 512-thread WGs on this toolchain, 3 spellings tested). Instead:
// U.x (A_DOTS) moves OUT of the lockstepped scan into helper WGs, one per
// (cell>=2, b). Helper computes A(t)=b_ih+U.x(t) (bitwise-identical chain) and
// streams it through a 32-slot fp32 ring in d_ws; scan l>=1 consumes A exactly
// like l0 consumes gx (loop-carried 1-step-ahead load). Scan's critical path
// shrinks to W.h + activations + barriers.
// Lags: l0 free -> helper_l1 (~12) -> scan_l1 (~8) -> helper_l2 -> scan_l2.
// Back-pressure: helper waits scan progress >= t-20 (ring 32, margin 9+).
__global__ __launch_bounds__(256, 1) __attribute__((amdgpu_waves_per_eu(1)))
void scan_gru(const float* __restrict__ h0,
              const float* __restrict__ w_hh0, const float* __restrict__ b_hh0,
              const float* __restrict__ w_ih12, const float* __restrict__ w_hh12,
              const float* __restrict__ b_ih12, const float* __restrict__ b_hh12,
              float* __restrict__ out, int* flags) {
  __shared__ __align__(16) float A_s[232], B_s[232];
  __shared__ __align__(16) _Float16 h16[80];
  __shared__ __align__(16) _Float16 xs[2][152];  // helper x staging (double-buffered)

  float* Aring = (float*)(flags + 256);  // 1KB offset; 32 slots x RINGSTRIDE floats
  const int tid = threadIdx.x;
  const int bi = blockIdx.x;

  if (bi < 144) {
    // ================= SCAN ROLE =================
    const int c = bi / NB, b = bi % NB;
    const int l = c >> 1, d = c & 1;
    const int ci = (l - 1) * 2 + d;
    const bool isgate = (tid < G3);
    const bool ish = (tid < NH);
    const int hj = tid;

    h8 Wa0 = zero8(), Wa1 = zero8(), Wa2 = zero8(), Wa3 = zero8(), Wa4 = zero8();
    h8 Wa5 = zero8(), Wa6 = zero8(), Wa7 = zero8(), Wa8 = zero8(), Wa9 = zero8();
    float bhha = 0.f;
    if (isgate) {
      const float* wA = (l == 0) ? w_hh0 + (size_t)(d * G3 + tid) * NH
                                 : w_hh12 + (size_t)(ci * G3 + tid) * NH;
      Wa0 = ld8f(wA, 0, NH);  Wa1 = ld8f(wA, 8, NH);  Wa2 = ld8f(wA, 16, NH);
      Wa3 = ld8f(wA, 24, NH); Wa4 = ld8f(wA, 32, NH); Wa5 = ld8f(wA, 40, NH);
      Wa6 = ld8f(wA, 48, NH); Wa7 = ld8f(wA, 56, NH); Wa8 = ld8f(wA, 64, NH);
      Wa9 = ld8f(wA, 72, NH);
      bhha = (l == 0) ? b_hh0[d * G3 + tid] : b_hh12[ci * G3 + tid];
    }

    float hreg = 0.f, hh0 = 0.f, hh1 = 0.f, hh2 = 0.f;
    if (ish) {
      hreg = h0[(size_t)(c * NB + b) * NH + hj];
      h16[hj] = (_Float16)hreg;
    }
    if (tid >= 225 && tid < 230) h16[NH + (tid - 225)] = (_Float16)0;

    // l0: loop-carried gx dword (unchanged). l>=1: loop-carried A value.
    const int n0 = d * G3 + tid;
    float cr = 0.f;
    if (l == 0 && isgate) cr = out[(size_t)b * OUTW + G3 + (n0 >> 1)];

    const int* fHp = (l > 0) ? &flags[144 + (c - 2) * NB + b] : flags;
    const int abase = (c - 2) * NB + b;  // valid only l>0
    int fvH = 0;
    float areg = 0.f;
    if (l > 0 && isgate) {
      while (ldflag(fHp) < 5) {}  // helper publishes quantized (8): A(0..7) ready
      areg = ldg_dev(&Aring[0 * RINGSTRIDE + abase * 225 + tid]);
      fvH = 5;
    }
    __syncthreads();

    for (int t = 0; t < LSEQ; t++) {
      // ---------- P1 ----------
      if (isgate) {
        if (l > 0) A_s[tid] = areg;  // A(t), prefetched last step
        PIN4(Wa0, Wa1, Wa2, Wa3); PIN4(Wa4, Wa5, Wa6, Wa7); PIN2(Wa8, Wa9);
        const h8* hv = (const h8*)h16;
        h8 H0 = hv[0], H1 = hv[1], H2 = hv[2], H3 = hv[3], H4 = hv[4];
        h8 H5 = hv[5], H6 = hv[6], H7 = hv[7], H8 = hv[8], H9 = hv[9];
        float b0a = dot8(Wa0, H0, bhha), b0b = dot8(Wa1, H1, 0.f);
        b0a = dot8(Wa2, H2, b0a); b0b = dot8(Wa3, H3, b0b);
        b0a = dot8(Wa4, H4, b0a); b0b = dot8(Wa5, H5, b0b);
        b0a = dot8(Wa6, H6, b0a); b0b = dot8(Wa7, H7, b0b);
        b0a = dot8(Wa8, H8, b0a); b0b = dot8(Wa9, H9, b0b);
        float accB = b0a + b0b;
        if (l == 0) {
          h2 pc = __builtin_bit_cast(h2, cr);
          float accA = (n0 & 1) ? (float)pc[1] : (float)pc[0];
          A_s[tid] = accA;
          if (t + 1 < LSEQ) cr = out[((size_t)(t + 1) * NB + b) * OUTW + G3 + (n0 >> 1)];
        } else {
          // flag gate for A(t+1..t+4) loads (A(tau) needs fH >= tau+1)
          if ((t & 3) == 0 && t + 1 < LSEQ) {
            int need = t + 5; if (need > LSEQ) need = LSEQ;
            if (fvH < need) { while (ldflag(fHp) < need) {} }
            fvH = ldflag(fHp);  // speculative refresh for the check at t+4
          }
          if (t + 1 < LSEQ) {
            areg = ldg_dev(&Aring[((t + 1) & (NRING - 1)) * RINGSTRIDE + abase * 225 + tid]);
          }
        }
        B_s[tid] = accB;
      }
      // progress/h publish (ALL cells): value t-4 => times <= t-5 confirmed
      if (tid == 0 && (t & 3) == 0 && t >= 8) stflag(&flags[c * NB + b], t - 4);
      WG_BARRIER();

      // ---------- P2 ----------
      if (ish) {
        float rg = sigm(A_s[hj] + B_s[hj]);
        float zg = sigm(A_s[NH + hj] + B_s[NH + hj]);
        float ng = tanh_f(A_s[2 * NH + hj] + rg * B_s[2 * NH + hj]);
        float hn = (1.f - zg) * ng + zg * hreg;
        hreg = hn;
        h16[hj] = (_Float16)hn;
        hh0 = ((t & 3) == 0) ? hn : hh0;
        hh1 = ((t & 3) == 1) ? hn : hh1;
        hh2 = ((t & 3) == 2) ? hn : hh2;
        if ((t & 3) == 3) {
          float* base = out + (size_t)(t - 3) * NB * OUTW + (size_t)b * OUTW + c * NH + hj;
          stg_dev(base, hh0);
          stg_dev(base + (size_t)NB * OUTW, hh1);
          stg_dev(base + 2 * (size_t)NB * OUTW, hh2);
          stg_dev(base + 3 * (size_t)NB * OUTW, hn);
          // vmcnt(5): newest 5 = [A/gx load, 4 stores]; confirms all OLDER
          // batches retired without waiting the in-flight prefetch load.
          asm volatile("s_waitcnt vmcnt(5)" ::: "memory");
        }
      }
      WG_BARRIER();
    }
    __syncthreads();
    if (tid == 0) stflag(&flags[c * NB + b], LSEQ);
  } else {
    // ================= HELPER ROLE: A(t) = b_ih + U.x(t) =================
    const int hidx = bi - 144;
    const int hc = 2 + hidx / NB, b = hidx % NB;
    const int l = hc >> 1;
    const int ci = (l - 1) * 2 + (hc & 1);
    const int u0 = (l - 1) * 2;

    h8 Ua0 = zero8(), Ua1 = zero8(), Ua2 = zero8(), Ua3 = zero8(), Ua4 = zero8();
    h8 Ua5 = zero8(), Ua6 = zero8(), Ua7 = zero8(), Ua8 = zero8(), Ua9 = zero8();
    h8 Ua10 = zero8(), Ua11 = zero8(), Ua12 = zero8(), Ua13 = zero8(), Ua14 = zero8();
    h8 Ua15 = zero8(), Ua16 = zero8(), Ua17 = zero8(), Ua18 = zero8();
    float biha = 0.f;
    if (tid < G3) {
      const float* uA = w_ih12 + (size_t)(ci * G3 + tid) * (2 * NH);
      Ua0 = ld8f(uA, 0, 150);   Ua1 = ld8f(uA, 8, 150);   Ua2 = ld8f(uA, 16, 150);
      Ua3 = ld8f(uA, 24, 150);  Ua4 = ld8f(uA, 32, 150);  Ua5 = ld8f(uA, 40, 150);
      Ua6 = ld8f(uA, 48, 150);  Ua7 = ld8f(uA, 56, 150);  Ua8 = ld8f(uA, 64, 150);
      Ua9 = ld8f(uA, 72, 150);  Ua10 = ld8f(uA, 80, 150); Ua11 = ld8f(uA, 88, 150);
      Ua12 = ld8f(uA, 96, 150); Ua13 = ld8f(uA, 104, 150); Ua14 = ld8f(uA, 112, 150);
      Ua15 = ld8f(uA, 120, 150); Ua16 = ld8f(uA, 128, 150); Ua17 = ld8f(uA, 136, 150);
      Ua18 = ld8f(uA, 144, 150);
      biha = b_ih12[ci * G3 + tid];
    }
    if (tid < 2) { xs[tid][150] = (_Float16)0; xs[tid][151] = (_Float16)0; }

    const int* f0p = &flags[u0 * NB + b];
    const int* f1p = &flags[(u0 + 1) * NB + b];
    const int* pPp = &flags[hc * NB + b];         // own-cell scan progress (back-pressure)
    int* fHo = &flags[144 + (hc - 2) * NB + b];   // own A-availability flag
    const int abase = (hc - 2) * NB + b;
    int fu0 = 0, fu1 = 0, fvP = 0;
    float xpA = 0.f, xpB = 0.f;

    // prologue: x(0), x(1) after upstream flag >= 2 (quantized -> 4)
    while (ldflag(f0p) < 2 || ldflag(f1p) < 2) {}
    if (tid < 150) {
      const float* xrow = out + (size_t)b * OUTW + u0 * NH + tid;
      xpA = ldg_dev(xrow);
      xpB = ldg_dev(xrow + (size_t)NB * OUTW);
    }
    __syncthreads();

    for (int t = 0; t < LSEQ; t++) {
      // stage x(t) into xs[t&1] (RNE cast, same as old xr path -> bitwise-identical)
      if (tid < 150) xs[t & 1][tid] = (_Float16)((t & 1) ? xpB : xpA);
      if ((t & 3) == 0) {
        // gate x(t+2..t+5) loads: x(tau) needs upstream flag >= tau+1
        if (t + 2 < LSEQ) {
          int need = t + 6; if (need > LSEQ) need = LSEQ;
          if (fu0 < need || fu1 < need) {
            while (ldflag(f0p) < need || ldflag(f1p) < need) {}
          }
        }
        // back-pressure: writes t..t+3 overwrite slots (t-32..t-29); scan
        // progress P=v => scan step >= v+4, A(<= v+5) loaded. P >= t-20 is ample.
        if (t >= 24) {
          int needP = t - 20;
          if (fvP < needP) { while (ldflag(pPp) < needP) {} }
        }
        fu0 = ldflag(f0p); fu1 = ldflag(f1p); fvP = ldflag(pPp);
      }
      // issue x(t+2) prefetch (consumed at t+2, same parity)
      if (tid < 150 && t + 2 < LSEQ) {
        float v = ldg_dev(&out[(size_t)(t + 2) * NB * OUTW + (size_t)b * OUTW + u0 * NH + tid]);
        if (t & 1) xpB = v; else xpA = v;
      }
      WG_BARRIER();
      // publish AFTER the barrier: all lanes' vmcnt(0) at t-1 precedes it.
      if (tid == 0 && (t & 3) == 0 && t >= 4) stflag(fHo, t);  // A(<= t-1) confirmed
      if (tid < G3) {
        PIN4(Ua0, Ua1, Ua2, Ua3); PIN4(Ua4, Ua5, Ua6, Ua7); PIN4(Ua8, Ua9, Ua10, Ua11);
        PIN4(Ua12, Ua13, Ua14, Ua15); PIN2(Ua16, Ua17); asm("" : "+v"(Ua18));
        const h8* xv = (const h8*)xs[t & 1];
        h8 X0 = xv[0], X1 = xv[1], X2 = xv[2], X3 = xv[3], X4 = xv[4];
        h8 X5 = xv[5], X6 = xv[6], X7 = xv[7], X8 = xv[8], X9 = xv[9];
        h8 X10 = xv[10], X11 = xv[11], X12 = xv[12], X13 = xv[13], X14 = xv[14];
        h8 X15 = xv[15], X16 = xv[16], X17 = xv[17], X18 = xv[18];
        float a0a = dot8(Ua0, X0, biha), a0b = dot8(Ua1, X1, 0.f);
        a0a = dot8(Ua2, X2, a0a);   a0b = dot8(Ua3, X3, a0b);
        a0a = dot8(Ua4, X4, a0a);   a0b = dot8(Ua5, X5, a0b);
        a0a = dot8(Ua6, X6, a0a);   a0b = dot8(Ua7, X7, a0b);
        a0a = dot8(Ua8, X8, a0a);   a0b = dot8(Ua9, X9, a0b);
        a0a = dot8(Ua10, X10, a0a); a0b = dot8(Ua11, X11, a0b);
        a0a = dot8(Ua12, X12, a0a); a0b = dot8(Ua13, X13, a0b);
        a0a = dot8(Ua14, X14, a0a); a0b = dot8(Ua15, X15, a0b);
        a0a = dot8(Ua16, X16, a0a); a0b = dot8(Ua17, X17, a0b);
        a0a = dot8(Ua18, X18, a0a);
        float val = a0a + a0b;  // bitwise == old in-scan A_DOTS result
        stg_dev(&Aring[(t & (NRING - 1)) * RINGSTRIDE + abase * 225 + tid], val);
      }
      if ((t & 3) == 3) asm volatile("s_waitcnt vmcnt(0)" ::: "memory");
    }
    asm volatile("s_waitcnt vmcnt(0)" ::: "memory");
    __syncthreads();
    if (tid == 0) stflag(fHo, LSEQ);  // A(<= LSEQ-1) all confirmed
  }
}

extern "C" void kernel_launch(void* const* d_in, const int* in_sizes, int n_in,
                              void* d_out, int out_size, void* d_ws, size_t ws_size,
                              hipStream_t stream) {
  const float* x      = (const float*)d_in[0];
  const float* h0     = (const float*)d_in[1];
  const float* w_ih0  = (const float*)d_in[2];
  const float* w_hh0  = (const float*)d_in[3];
  const float* b_ih0  = (const float*)d_in[4];
  const float* b_hh0  = (const float*)d_in[5];
  const float* w_ih12 = (const float*)d_in[6];
  const float* w_hh12 = (const float*)d_in[7];
  const float* b_ih12 = (const float*)d_in[8];
  const float* b_hh12 = (const float*)d_in[9];
  float* out = (float*)d_out;
  int* flags = (int*)d_ws;

  hipLaunchKernelGGL(init_flags, dim3(1), dim3(256), 0, stream, flags);
  hipLaunchKernelGGL(gemm_gx, dim3(768), dim3(256), 0, stream, x, w_ih0, b_ih0, out);
  hipLaunchKernelGGL(scan_gru, dim3(240), dim3(256), 0, stream,
                     h0, w_hh0, b_hh0, w_ih12, w_hh12, b_ih12, b_hh12, out, flags);
}